// Round 4
// baseline (2074.641 us; speedup 1.0000x reference)
//
#include <hip/hip_runtime.h>
#include <hip/hip_bf16.h>

// QLSTM: SEQ=1024, B=64, D_IN=256, D_H=256, fp32 in/out.
// Phase 1: Xp = x @ Wx + bias  (f16 MFMA GEMM, no sequential dep)
// Phase 2: 64 independent recurrences, 1 WG (512 thr, 8 waves) per batch.
//   Thread (p = tid>>8, h = tid&255) owns 2 gate-cols: p=0 -> {f,i}, p=1 -> {g,o}.
//   Wh rows 0..191  -> VGPRs (2 cols * 24 uint4 = 192 regs)
//   Wh rows 192..255-> LDS (128 KB)
//   hx: one ds_read_b64/lane, then v_readlane -> SGPR feeding v_dot2_f32_f16.
// Round-1 lesson: >256 regs/thread spills to scratch.
// Round-2 lesson: streaming weights through L1 = 64 B/cyc/CU wall.
// Round-3 lesson: __launch_bounds__(512,2) alone -> allocator picked 128 regs
//   and SANK the weight loads back into the loop (VGPR_Count=128). Fix:
//   amdgpu_waves_per_eu(2,2) + empty-asm pins each iteration.

typedef _Float16 f16;
typedef _Float16 f16x2 __attribute__((ext_vector_type(2)));
typedef _Float16 f16x4 __attribute__((ext_vector_type(4)));
typedef _Float16 f16x8 __attribute__((ext_vector_type(8)));
typedef float f32x4 __attribute__((ext_vector_type(4)));

#define SEQ 1024
#define BATCH 64
#define DIN 256
#define DH 256
#define NCOL 1024
#define RV 192           // rows in VGPRs (24 chunks of 8)
#define RVC 24
#define RLC 8            // LDS chunks (64 rows)

// ---- ws layout (bytes) ----
#define WXP_OFF   0u                 // f16 [32][1024][8]
#define WHV_OFF   524288u            // f16 [1024 cols][192 rows]
#define WHL_OFF   917504u            // f16 [8][1024][8]
#define BIAS_OFF  1048576u           // f32 [1024]
#define HXS_OFF   1052672u           // f16 [64][256]
#define CXS_OFF   1085440u           // f32 [64][256]
#define XP_OFF    1150976u           // f16 [Tc*64][1024]

#define SEQ_LDS_BYTES 134144         // 131072 wts + 1024 hx + 2048 exch

#define PIN4(v) asm volatile("" : "+v"(v.x), "+v"(v.y), "+v"(v.z), "+v"(v.w))

__device__ __forceinline__ float dot2(unsigned int h, unsigned int w, float acc) {
#if __has_builtin(__builtin_amdgcn_fdot2)
  return __builtin_amdgcn_fdot2(__builtin_bit_cast(f16x2, h),
                                __builtin_bit_cast(f16x2, w), acc, false);
#else
  f16x2 a = __builtin_bit_cast(f16x2, h);
  f16x2 b = __builtin_bit_cast(f16x2, w);
  return acc + (float)a[0] * (float)b[0] + (float)a[1] * (float)b[1];
#endif
}

__device__ __forceinline__ float fast_sigmoid(float x) {
  float e = __expf(-x);
  return __builtin_amdgcn_rcpf(1.0f + e);
}
__device__ __forceinline__ float fast_tanh(float x) {
  x = fminf(fmaxf(x, -15.0f), 15.0f);
  float e = __expf(2.0f * x);
  return (e - 1.0f) * __builtin_amdgcn_rcpf(e + 1.0f);
}

// ---------------- prep: convert / repack weights ----------------
__global__ void qlstm_prep(const float* __restrict__ Wf, const float* __restrict__ Wi,
                           const float* __restrict__ Wg, const float* __restrict__ Wo,
                           const float* __restrict__ bf_, const float* __restrict__ bi_,
                           const float* __restrict__ bg_, const float* __restrict__ bo_,
                           f16* __restrict__ Wxp, f16* __restrict__ WhV,
                           f16* __restrict__ WhL, float* __restrict__ biasp) {
  int tid = blockIdx.x * 256 + threadIdx.x;
  if (tid < 4 * 512 * 256) {
    int g = tid >> 17;
    int rem = tid & 131071;
    int k = rem >> 8, n = rem & 255;
    const float* W = (g == 0) ? Wf : (g == 1) ? Wi : (g == 2) ? Wg : Wo;
    float v = W[k * 256 + n];
    int j = (g << 8) + n;
    f16 hv = (f16)v;
    if (k < 256) {
      Wxp[((size_t)(k >> 3) * 1024 + j) * 8 + (k & 7)] = hv;
    } else {
      int kk = k - 256;
      if (kk < RV) {
        WhV[(size_t)j * RV + kk] = hv;
      } else {
        int r = kk - RV;
        WhL[((size_t)(r >> 3) * 1024 + j) * 8 + (r & 7)] = hv;
      }
    }
  }
  if (tid < 1024) {
    int g = tid >> 8, n = tid & 255;
    const float* bb = (g == 0) ? bf_ : (g == 1) ? bi_ : (g == 2) ? bg_ : bo_;
    biasp[tid] = bb[n];
  }
}

// ---------------- phase 1: Xp = x @ Wx + bias  (MFMA f16) ----------------
__global__ __launch_bounds__(256) void qlstm_xproj(
    const float* __restrict__ X, const f16* __restrict__ Wxp,
    const float* __restrict__ biasp, f16* __restrict__ Xp) {
  __shared__ f16 As[128][72];
  __shared__ f16 Bs[8 * 128 * 8];

  int tid = threadIdx.x;
  int tm = blockIdx.x, tn = blockIdx.y;
  int wave = tid >> 6, lane = tid & 63;
  int qm = (wave & 1) * 64, qn = (wave >> 1) * 64;
  int lm = lane & 15, lk = lane >> 4;

  f32x4 acc[4][4];
#pragma unroll
  for (int a = 0; a < 4; ++a)
#pragma unroll
    for (int b = 0; b < 4; ++b) acc[a][b] = (f32x4)0.0f;

  for (int k0 = 0; k0 < 256; k0 += 64) {
    {
      int r = tid >> 1, c0 = (tid & 1) * 32;
      const float4* src = (const float4*)(X + (size_t)(tm * 128 + r) * 256 + k0 + c0);
#pragma unroll
      for (int i = 0; i < 8; ++i) {
        float4 v = src[i];
        f16x4 pk = {(f16)v.x, (f16)v.y, (f16)v.z, (f16)v.w};
        *(f16x4*)&As[r][c0 + i * 4] = pk;
      }
    }
    {
#pragma unroll
      for (int it = 0; it < 4; ++it) {
        int idx = it * 256 + tid;
        int kgi = idx >> 7, n = idx & 127;
        ((uint4*)Bs)[idx] =
            *(const uint4*)(Wxp + (((size_t)(k0 >> 3) + kgi) * 1024 + tn * 128 + n) * 8);
      }
    }
    __syncthreads();
#pragma unroll
    for (int ks = 0; ks < 2; ++ks) {
      f16x8 af[4], bfr[4];
#pragma unroll
      for (int mi = 0; mi < 4; ++mi)
        af[mi] = *(const f16x8*)&As[qm + mi * 16 + lm][ks * 32 + lk * 8];
#pragma unroll
      for (int ni = 0; ni < 4; ++ni)
        bfr[ni] = *(const f16x8*)&Bs[(((ks * 4 + lk) * 128) + qn + ni * 16 + lm) * 8];
#pragma unroll
      for (int mi = 0; mi < 4; ++mi)
#pragma unroll
        for (int ni = 0; ni < 4; ++ni)
          acc[mi][ni] = __builtin_amdgcn_mfma_f32_16x16x32_f16(af[mi], bfr[ni],
                                                               acc[mi][ni], 0, 0, 0);
    }
    __syncthreads();
  }
  int m0 = tm * 128 + qm, j0 = tn * 128 + qn;
#pragma unroll
  for (int mi = 0; mi < 4; ++mi)
#pragma unroll
    for (int ni = 0; ni < 4; ++ni) {
      int j = j0 + ni * 16 + lm;
      float bv = biasp[j];
#pragma unroll
      for (int r = 0; r < 4; ++r) {
        int m = m0 + mi * 16 + lk * 4 + r;
        Xp[(size_t)m * 1024 + j] = (f16)(acc[mi][ni][r] + bv);
      }
    }
}

// ---------------- phase 2: sequential LSTM ----------------
__global__ __launch_bounds__(512)
__attribute__((amdgpu_waves_per_eu(2, 2)))
void qlstm_seq(
    const f16* __restrict__ Xp, const f16* __restrict__ WhV,
    const f16* __restrict__ WhL,
    float* __restrict__ out, f16* __restrict__ hxs, float* __restrict__ cxs,
    float* __restrict__ hxout, float* __restrict__ cxout, int t0, int t1) {
  extern __shared__ char smem[];
  f16* wlds = (f16*)smem;                    // 131072 B: [8][1024][8]
  f16* hxb = (f16*)(smem + 131072);          // [2][256]
  float2* exch = (float2*)(smem + 132096);   // [256]

  int tid = threadIdx.x;
  int p = tid >> 8, h = tid & 255;
  int lane = tid & 63;
  int b = blockIdx.x;
  int j0 = p * 512 + h;          // p=0: f-gate col; p=1: g-gate col
  int j1 = j0 + 256;             // p=0: i-gate col; p=1: o-gate col

  // stage LDS weights (8192 uint4 over 512 threads)
  {
    const uint4* src = (const uint4*)WhL;
    uint4* dst = (uint4*)wlds;
#pragma unroll
    for (int i = 0; i < 16; ++i) dst[i * 512 + tid] = src[i * 512 + tid];
  }

  // VGPR-resident weights: 2 cols x 24 uint4 = 192 regs
  uint4 wr0[RVC], wr1[RVC];
  {
    const uint4* q0 = (const uint4*)WhV + (size_t)j0 * RVC;
    const uint4* q1 = (const uint4*)WhV + (size_t)j1 * RVC;
#pragma unroll
    for (int c = 0; c < RVC; ++c) { wr0[c] = q0[c]; wr1[c] = q1[c]; }
  }

  float cx = 0.0f;
  if (p == 0) {
    if (t0 == 0) {
      hxb[h] = (f16)0.0f;
    } else {
      hxb[h] = hxs[b * 256 + h];
      cx = cxs[b * 256 + h];
    }
  }

  const f16* xpb = Xp + (size_t)b * 1024;
  f16 xa = xpb[j0], xb_ = xpb[j1];

  __syncthreads();

  float hv = 0.0f;
  for (int t = t0; t < t1; ++t) {
    // pin weight regs: asm "writes" them each iteration so the loads can
    // never be sunk into the loop (round-3 failure mode)
#pragma unroll
    for (int c = 0; c < RVC; ++c) { PIN4(wr0[c]); PIN4(wr1[c]); }

    int par = t & 1;
    // whole hx into the wave: lane l holds hx[4l..4l+4)
    uint2 hl = *(const uint2*)(hxb + par * 256 + lane * 4);

    float a0 = (float)xa, a1 = (float)xb_;

    // prefetch next step's Xp (independent of recurrence)
    int tnx = (t + 1 < t1) ? (t + 1 - t0) : (t - t0);
    const f16* xq = Xp + (size_t)tnx * (BATCH * NCOL) + (size_t)b * 1024;
    f16 xna = xq[j0], xnb = xq[j1];

    // rows 0..191 from VGPR weights; hx via readlane -> SGPR operand of v_dot2
#pragma unroll
    for (int c = 0; c < RVC; ++c) {
      unsigned s0 = (unsigned)__builtin_amdgcn_readlane((int)hl.x, 2 * c);
      unsigned s1 = (unsigned)__builtin_amdgcn_readlane((int)hl.y, 2 * c);
      unsigned s2 = (unsigned)__builtin_amdgcn_readlane((int)hl.x, 2 * c + 1);
      unsigned s3 = (unsigned)__builtin_amdgcn_readlane((int)hl.y, 2 * c + 1);
      a0 = dot2(s0, wr0[c].x, a0); a0 = dot2(s1, wr0[c].y, a0);
      a0 = dot2(s2, wr0[c].z, a0); a0 = dot2(s3, wr0[c].w, a0);
      a1 = dot2(s0, wr1[c].x, a1); a1 = dot2(s1, wr1[c].y, a1);
      a1 = dot2(s2, wr1[c].z, a1); a1 = dot2(s3, wr1[c].w, a1);
    }
    // rows 192..255 from LDS
#pragma unroll
    for (int c = 0; c < RLC; ++c) {
      int cc = RVC + c;
      unsigned s0 = (unsigned)__builtin_amdgcn_readlane((int)hl.x, 2 * cc);
      unsigned s1 = (unsigned)__builtin_amdgcn_readlane((int)hl.y, 2 * cc);
      unsigned s2 = (unsigned)__builtin_amdgcn_readlane((int)hl.x, 2 * cc + 1);
      unsigned s3 = (unsigned)__builtin_amdgcn_readlane((int)hl.y, 2 * cc + 1);
      uint4 w0 = ((const uint4*)wlds)[(size_t)c * 1024 + j0];
      uint4 w1 = ((const uint4*)wlds)[(size_t)c * 1024 + j1];
      a0 = dot2(s0, w0.x, a0); a0 = dot2(s1, w0.y, a0);
      a0 = dot2(s2, w0.z, a0); a0 = dot2(s3, w0.w, a0);
      a1 = dot2(s0, w1.x, a1); a1 = dot2(s1, w1.y, a1);
      a1 = dot2(s2, w1.z, a1); a1 = dot2(s3, w1.w, a1);
    }

    if (p == 1) exch[h] = make_float2(a0, a1);   // (g, o) pre-activations
    __syncthreads();
    if (p == 0) {
      float2 go = exch[h];
      float vf = fast_sigmoid(a0);
      float vi = fast_sigmoid(a1);
      float vg = fast_tanh(go.x);
      float vo = fast_sigmoid(go.y);
      cx = fmaf(vf, cx, vi * vg);
      hv = vo * fast_tanh(cx);
      out[((size_t)t * BATCH + b) * 256 + h] = hv;
      hxb[(par ^ 1) * 256 + h] = (f16)hv;
    }
    __syncthreads();

    xa = xna; xb_ = xnb;
  }

  if (p == 0) {
    hxs[b * 256 + h] = (f16)hv;
    cxs[b * 256 + h] = cx;
    if (t1 == SEQ) {
      hxout[b * 256 + h] = hv;
      cxout[b * 256 + h] = cx;
    }
  }
}

extern "C" void kernel_launch(void* const* d_in, const int* in_sizes, int n_in,
                              void* d_out, int out_size, void* d_ws, size_t ws_size,
                              hipStream_t stream) {
  const float* X  = (const float*)d_in[0];
  const float* Wf = (const float*)d_in[1]; const float* bf_ = (const float*)d_in[2];
  const float* Wi = (const float*)d_in[3]; const float* bi_ = (const float*)d_in[4];
  const float* Wg = (const float*)d_in[5]; const float* bg_ = (const float*)d_in[6];
  const float* Wo = (const float*)d_in[7]; const float* bo_ = (const float*)d_in[8];
  float* out = (float*)d_out;

  char* ws = (char*)d_ws;
  f16*   Wxp   = (f16*)(ws + WXP_OFF);
  f16*   WhV   = (f16*)(ws + WHV_OFF);
  f16*   WhL   = (f16*)(ws + WHL_OFF);
  float* biasp = (float*)(ws + BIAS_OFF);
  f16*   hxs   = (f16*)(ws + HXS_OFF);
  float* cxs   = (float*)(ws + CXS_OFF);
  f16*   Xp    = (f16*)(ws + XP_OFF);

  size_t avail = (ws_size > XP_OFF) ? (ws_size - XP_OFF) : 0;
  int Tc = SEQ;
  while (Tc > 2 && (size_t)Tc * BATCH * NCOL * 2 > avail) Tc >>= 1;

  qlstm_prep<<<2048, 256, 0, stream>>>(Wf, Wi, Wg, Wo, bf_, bi_, bg_, bo_,
                                       Wxp, WhV, WhL, biasp);

  (void)hipFuncSetAttribute((const void*)qlstm_seq,
                            hipFuncAttributeMaxDynamicSharedMemorySize,
                            SEQ_LDS_BYTES);

  float* hxout = out + (size_t)SEQ * BATCH * DH;
  float* cxout = hxout + BATCH * DH;

  for (int t0 = 0; t0 < SEQ; t0 += Tc) {
    dim3 g1(Tc * BATCH / 128, NCOL / 128);
    qlstm_xproj<<<g1, 256, 0, stream>>>(X + (size_t)t0 * BATCH * DIN, Wxp, biasp, Xp);
    qlstm_seq<<<BATCH, 512, SEQ_LDS_BYTES, stream>>>(Xp, WhV, WhL, out, hxs, cxs,
                                                     hxout, cxout, t0, t0 + Tc);
  }
}